// Round 7
// baseline (15760.500 us; speedup 1.0000x reference)
//
#include <hip/hip_runtime.h>
#include <math.h>

// ---------------------------------------------------------------------------
// TensorProcessor: conv3d(1,3,1)+bias+relu -> Tucker-HOOI core (8,6,6,6)
// Round 7: row-per-thread eigh (128 threads = 2 waves). Thread k owns row k
// in VGPRs; u/w broadcast via LDS once per step; 5 cheap 2-wave barriers.
// Scalar Householder formulas identical to R1-R6; symv order = R1-R3
// ascending chain; update expression = R4-R6 symmetric-exact form.
// Non-eigh kernels unchanged from R6.
// ---------------------------------------------------------------------------

// ws layout (float offsets)
constexpr long long OFF_T   = 0LL;                 // 26,214,400
constexpr long long OFF_TC  = 26214400LL;          // 6,553,600
constexpr long long OFF_TB  = 32768000LL;          // 1,572,864
constexpr long long OFF_PART= OFF_TC;              // 240*16384 (init only)
constexpr long long OFF_TD0a= OFF_TC;              // mode0 (32,6,6,64)=73,728
constexpr long long OFF_TD0b= OFF_TC + 131072;     // mode0 (32,6,6,6)=6,912
constexpr long long OFF_TD  = OFF_TB + 1000000LL;  // sweep small tensors
constexpr long long OFF_G0  = OFF_TB + 1400000LL;  // 1,024
constexpr long long OFF_G1  = OFF_G0 + 1024;       // 10,000
constexpr long long OFF_G2  = OFF_G1 + 10000;      // 16,384
constexpr long long OFF_G3  = OFF_G2 + 16384;      // 4,096
constexpr long long OFF_F0  = 34340864LL;          // 256
constexpr long long OFF_F1  = OFF_F0 + 256;        // 600
constexpr long long OFF_F2  = OFF_F1 + 600;        // 768
constexpr long long OFF_F3  = OFF_F2 + 768;        // 384

// ---------------- conv + relu ----------------
__global__ void kconv(const float* __restrict__ x, const float* __restrict__ cw,
                      const float* __restrict__ cb, float* __restrict__ t) {
  int idx = blockIdx.x * blockDim.x + threadIdx.x;
  if (idx >= 26214400) return;
  int w  = idx & 63;
  int h  = (idx >> 6) & 127;
  int d  = (idx >> 13) % 100;
  int o  = idx / 819200;
  float acc = cb[o];
#pragma unroll
  for (int i = 0; i < 4; ++i) {
    const float* xi = x + (((long long)i * 100 + d) * 130 + h) * 64 + w;
#pragma unroll
    for (int kh = 0; kh < 3; ++kh)
      acc = fmaf(cw[(o * 4 + i) * 3 + kh], xi[kh * 64], acc);
  }
  t[idx] = fmaxf(acc, 0.f);
}

// ---------------- big gram (init HOSVD): G = X X^T over fibers ----------------
#define GRAM_BLOCKS 240
template<int D, long long QQ, bool TRANS>
__global__ void kgram_big(const float* __restrict__ T, float* __restrict__ part,
                          int P) {
  constexpr int C = 64;
  constexpr int SUB = (D + 63) / 64;
  constexpr int DP = SUB * 64;
  __shared__ float tile[DP * (C + 1)];
  const int tid = threadIdx.x;                 // 256
  const int ta = tid >> 4, tb = tid & 15;
  float acc[SUB][SUB][4][4];
#pragma unroll
  for (int a = 0; a < SUB; ++a)
#pragma unroll
    for (int b = 0; b < SUB; ++b)
#pragma unroll
      for (int i = 0; i < 4; ++i)
#pragma unroll
        for (int j = 0; j < 4; ++j) acc[a][b][i][j] = 0.f;

  const long long nfib = (long long)P * QQ;
  const int nchunk = (int)(nfib / C);
  for (int ch = blockIdx.x; ch < nchunk; ch += gridDim.x) {
    const long long base = (long long)ch * C;
    __syncthreads();
    if (TRANS) {
      for (int e = tid; e < D * C; e += 256) {
        int a = e & 63, cc = e >> 6;
        tile[a * (C + 1) + cc] = T[base * D + e];
      }
    } else {
      for (int e = tid; e < DP * C; e += 256) {
        int a = e / C, cc = e % C;
        float v = 0.f;
        if (a < D) {
          long long f = base + cc;
          long long p = f / QQ, q = f - p * QQ;   // compile-time QQ
          v = T[(p * D + a) * QQ + q];
        }
        tile[a * (C + 1) + cc] = v;
      }
    }
    __syncthreads();
    for (int cc = 0; cc < C; ++cc) {
      float av[SUB][4], bv[SUB][4];
#pragma unroll
      for (int si = 0; si < SUB; ++si)
#pragma unroll
        for (int i = 0; i < 4; ++i) av[si][i] = tile[(si * 64 + ta * 4 + i) * (C + 1) + cc];
#pragma unroll
      for (int sj = 0; sj < SUB; ++sj)
#pragma unroll
        for (int j = 0; j < 4; ++j) bv[sj][j] = tile[(sj * 64 + tb * 4 + j) * (C + 1) + cc];
#pragma unroll
      for (int si = 0; si < SUB; ++si)
#pragma unroll
        for (int sj = 0; sj < SUB; ++sj)
#pragma unroll
          for (int i = 0; i < 4; ++i)
#pragma unroll
            for (int j = 0; j < 4; ++j)
              acc[si][sj][i][j] = fmaf(av[si][i], bv[sj][j], acc[si][sj][i][j]);
    }
  }
  float* pb = part + (long long)blockIdx.x * D * D;
  for (int si = 0; si < SUB; ++si)
    for (int i = 0; i < 4; ++i) {
      int a = si * 64 + ta * 4 + i;
      if (a >= D) continue;
      for (int sj = 0; sj < SUB; ++sj)
        for (int j = 0; j < 4; ++j) {
          int b = sj * 64 + tb * 4 + j;
          if (b >= D) continue;
          pb[a * D + b] = acc[si][sj][i][j];
        }
    }
}

__global__ void kreduce(const float* __restrict__ part, float* __restrict__ G, int DD) {
  int i = blockIdx.x * blockDim.x + threadIdx.x;
  if (i >= DD) return;
  float s = 0.f;
  for (int b = 0; b < GRAM_BLOCKS; ++b) s += part[(long long)b * DD + i];
  G[i] = s;
}

// ---------------- small gram (projected Y) ----------------
__global__ void kgram_small(const float* __restrict__ Y, float* __restrict__ G,
                            int P, int d, int Q) {
  int pair = blockIdx.x * blockDim.x + threadIdx.x;
  if (pair >= d * d) return;
  int a = pair / d, b = pair % d;
  float s = 0.f;
  for (int p = 0; p < P; ++p) {
    const float* ya = Y + ((long long)p * d + a) * Q;
    const float* yb = Y + ((long long)p * d + b) * Q;
    for (int q = 0; q < Q; ++q) s = fmaf(ya[q], yb[q], s);
  }
  G[pair] = s;
}

// ---------------- mode contraction: out[p,j,q] = sum_a F[a,j] in[p,a,q] ----------------
template<int R, long long QV>
__global__ void kcontract(const float* __restrict__ in, const float* __restrict__ F,
                          float* __restrict__ out, int P, int d) {
  long long total = (long long)P * QV;
  long long idx = (long long)blockIdx.x * blockDim.x + threadIdx.x;
  if (idx >= total) return;
  long long p = idx / QV, q = idx - p * QV;
  float acc[R];
#pragma unroll
  for (int j = 0; j < R; ++j) acc[j] = 0.f;
  const float* ip = in + (p * d) * QV + q;
  for (int a = 0; a < d; ++a) {
    float v = ip[(long long)a * QV];
#pragma unroll
    for (int j = 0; j < R; ++j) acc[j] = fmaf(F[a * R + j], v, acc[j]);
  }
  float* op = out + (p * R) * QV + q;
#pragma unroll
  for (int j = 0; j < R; ++j) op[(long long)j * QV] = acc[j];
}

// ---------------- eigh: top-r eigenvectors of symmetric G (n<=128) ----------------
#define EIG_THREADS 128
#define EIG_WAVES 2

struct __align__(16) ESm {
  float ApkL[8256];              // packed-lower Householder columns (export)
  float colbuf[128];             // current pivot column
  float uu[128];                 // Householder vector u
  float wwf[128];                // final w vector
  float dd[128], ee[128], e2s[128];
  float taus[128], scls[128];
  float vt[8][129];
  float slv[8][385];
  float lam[8];
  float red[EIG_WAVES];
  float sca[4];
};

__device__ __forceinline__ float blkReduceSum(float v, volatile float* red, int tid) {
  __syncthreads();
#pragma unroll
  for (int off = 32; off > 0; off >>= 1) v += __shfl_down(v, off, 64);
  if ((tid & 63) == 0) red[tid >> 6] = v;
  __syncthreads();
  float s = 0.f;
#pragma unroll
  for (int w = 0; w < EIG_WAVES; ++w) s += red[w];
  return s;
}

template<int N, int RR>
__device__ void eig_body(ESm& S, const float* __restrict__ G, float* __restrict__ F) {
  constexpr int NC4 = N / 4;           // float4 chunks per row (N%4==0 for 32/64/100/128)
  const int tid  = threadIdx.x;
  const int lane = tid & 63, wid = tid >> 6;
  const bool act = (tid < N);

  // ---- load: thread k owns row k of the symmetric matrix in VGPRs ----
  float Ar[N];
  if (act) {
    const float4* g4 = (const float4*)(G + tid * N);   // rows 16B-aligned (N%4==0)
#pragma unroll
    for (int c = 0; c < NC4; ++c) {
      float4 t = g4[c];
      Ar[4*c] = t.x; Ar[4*c+1] = t.y; Ar[4*c+2] = t.z; Ar[4*c+3] = t.w;
    }
  } else {
#pragma unroll
    for (int j = 0; j < N; ++j) Ar[j] = 0.f;
  }
  if (tid == 0) {                      // colbuf <- column 0 = row 0
    float4* cb4 = (float4*)S.colbuf;
#pragma unroll
    for (int c = 0; c < NC4; ++c)
      cb4[c] = make_float4(Ar[4*c], Ar[4*c+1], Ar[4*c+2], Ar[4*c+3]);
  }

  // ---- Householder tridiagonalization (LAPACK slarfg conventions) ----
  for (int i = 0; i <= N - 3; ++i) {
    __syncthreads();                                   // B1: colbuf visible
    float ck = act ? S.colbuf[tid] : 0.f;
    float alpha = S.colbuf[i + 1];
    float prt = (act && tid >= i + 2) ? ck * ck : 0.f;
#pragma unroll
    for (int off = 32; off > 0; off >>= 1) prt += __shfl_down(prt, off, 64);
    if (lane == 0) S.red[wid] = prt;
    __syncthreads();                                   // B2
    float xnorm2 = S.red[0] + S.red[1];
    float beta, tau_i, scl_i;
    if (xnorm2 == 0.f) { beta = alpha; tau_i = 0.f; scl_i = 0.f; }
    else {
      float an = sqrtf(alpha * alpha + xnorm2);
      beta = (alpha >= 0.f) ? -an : an;
      tau_i = (beta - alpha) / beta;
      scl_i = 1.f / (alpha - beta);
    }
    float u_k = 0.f;
    if (act) {
      if (tid == i + 1) u_k = 1.f;
      else if (tid >= i + 2) u_k = ck * scl_i;
    }
    S.uu[tid] = u_k;                                   // pad rows write exact 0
    __syncthreads();                                   // B3: uu visible
    // symv: ascending l chain (l<=i terms are exact fma no-ops, u=0)
    const float4* uu4 = (const float4*)S.uu;
    float s = 0.f;
#pragma unroll
    for (int c = 0; c < NC4; ++c) {
      float4 t = uu4[c];
      s = fmaf(Ar[4*c+0], t.x, s);
      s = fmaf(Ar[4*c+1], t.y, s);
      s = fmaf(Ar[4*c+2], t.z, s);
      s = fmaf(Ar[4*c+3], t.w, s);
    }
    float w_pre = (act && tid >= i + 1) ? tau_i * s : 0.f;
    float p2 = w_pre * u_k;                            // exact gate
#pragma unroll
    for (int off = 32; off > 0; off >>= 1) p2 += __shfl_down(p2, off, 64);
    if (lane == 0) S.red[wid] = p2;
    __syncthreads();                                   // B4
    float pu = S.red[0] + S.red[1];
    float halfc = -0.5f * tau_i * pu;
    float w_k = w_pre + halfc * u_k;
    S.wwf[tid] = w_k;                                  // pad rows write exact 0
    __syncthreads();                                   // B5: wwf visible
    // trailing update: symmetric-exact expression (R4-R6)
    const float4* ww4 = (const float4*)S.wwf;
#pragma unroll
    for (int c = 0; c < NC4; ++c) {
      float4 tu = uu4[c];
      float4 tw = ww4[c];
      Ar[4*c+0] -= __fadd_rn(__fmul_rn(u_k, tw.x), __fmul_rn(w_k, tu.x));
      Ar[4*c+1] -= __fadd_rn(__fmul_rn(u_k, tw.y), __fmul_rn(w_k, tu.y));
      Ar[4*c+2] -= __fadd_rn(__fmul_rn(u_k, tw.z), __fmul_rn(w_k, tu.z));
      Ar[4*c+3] -= __fadd_rn(__fmul_rn(u_k, tw.w), __fmul_rn(w_k, tu.w));
    }
    if (tid == i + 1) {                                // next pivot column = my row
      float4* cb4 = (float4*)S.colbuf;
#pragma unroll
      for (int c = 0; c < NC4; ++c)
        cb4[c] = make_float4(Ar[4*c], Ar[4*c+1], Ar[4*c+2], Ar[4*c+3]);
    }
    if (tid == 0) { S.ee[i] = beta; S.taus[i] = tau_i; S.scls[i] = scl_i; }
  }
  __syncthreads();

  // ---- export diag + packed-lower Householder columns + last off-diag ----
  if (act) {
    int base = (tid * (tid - 1)) >> 1;
#pragma unroll
    for (int l = 0; l < N; ++l) {
      if (l == tid) S.dd[tid] = Ar[l];
      if (l < tid)  S.ApkL[base + l] = Ar[l];
    }
    if (tid == N - 1) S.ee[N - 2] = Ar[N - 2];
  }
  __syncthreads();
  if (tid < N) S.e2s[tid] = (tid >= 1) ? S.ee[tid - 1] * S.ee[tid - 1] : 0.f;

  // ---- Gershgorin bounds + pivmin ----
  if (tid == 0) {
    float lo = 3.4e38f, hi = -3.4e38f, me2 = 0.f;
    for (int ii = 0; ii < N; ++ii) {
      float rad = 0.f;
      if (ii > 0) rad += fabsf(S.ee[ii - 1]);
      if (ii < N - 1) { rad += fabsf(S.ee[ii]); me2 = fmaxf(me2, S.ee[ii] * S.ee[ii]); }
      lo = fminf(lo, S.dd[ii] - rad);
      hi = fmaxf(hi, S.dd[ii] + rad);
    }
    float span = hi - lo;
    S.sca[0] = lo - 0.001f * span - 1e-20f;
    S.sca[1] = hi + 0.001f * span + 1e-20f;
    S.sca[2] = 1.1754944e-38f * fmaxf(1.f, me2);
  }
  __syncthreads();
  const float pivmin = S.sca[2];

  // ---- 33-way multisection: 32 threads per eigenvalue, groups of 4 ----
  for (int base = 0; base < RR; base += 4) {
    const int grp = base + (tid >> 5);
    const int gt = tid & 31;
    if (grp < RR) {
      const int krank = N - 1 - grp;
      float lo = S.sca[0], hi = S.sca[1];
      for (int round = 0; round < 8; ++round) {
        float w = (hi - lo) * (1.f / 33.f);
        float sg = fmaf(w, (float)(gt + 1), lo);
        int cnt = 0;
        float qq = S.dd[0] - sg;
        if (qq < 0.f) cnt++;
        for (int ii = 1; ii < N; ++ii) {
          if (fabsf(qq) < pivmin) qq = -pivmin;
          qq = S.dd[ii] - sg - S.e2s[ii] / qq;
          if (qq < 0.f) cnt++;
        }
        float nlo = (cnt <= krank) ? sg : lo;
        float nhi = (cnt >  krank) ? sg : hi;
#pragma unroll
        for (int off = 16; off > 0; off >>= 1) {
          nlo = fmaxf(nlo, __shfl_down(nlo, off, 32));
          nhi = fminf(nhi, __shfl_down(nhi, off, 32));
        }
        nlo = __shfl(nlo, 0, 32);
        nhi = __shfl(nhi, 0, 32);
        lo = fminf(nlo, nhi); hi = fmaxf(nlo, nhi);
      }
      if (gt == 0) S.lam[grp] = 0.5f * (lo + hi) * (1.f + (float)grp * 3e-7f);
    }
  }
  __syncthreads();

  // ---- inverse iteration, register-carried recurrence ----
  if (tid < RR) {
    const int j = tid;
    float* u0 = &S.slv[j][0];
    float* u1 = &S.slv[j][128];
    float* u2 = &S.slv[j][256];
    float* vv = &S.vt[j][0];
    const float lj = S.lam[j];
    for (int k = 0; k < N; ++k) vv[k] = 1.f;
    for (int itr = 0; itr < 3; ++itr) {
      float d = S.dd[0] - lj;
      float e = S.ee[0];
      float cv = vv[0];
      for (int i = 0; i < N - 1; ++i) {
        float bi = S.ee[i];
        float d1 = S.dd[i + 1] - lj;
        float e1 = (i + 1 < N - 1) ? S.ee[i + 1] : 0.f;
        float vnext = vv[i + 1];
        float ai = d, ci = e;
        if (fabsf(ai) >= fabsf(bi)) {
          if (fabsf(ai) < pivmin) ai = (ai >= 0.f ? pivmin : -pivmin);
          float m = bi / ai;
          u0[i] = ai; u1[i] = ci; u2[i] = 0.f;
          d = d1 - m * ci;
          e = e1;
          vv[i] = cv;
          cv = vnext - m * cv;
        } else {
          float m = ai / bi;
          u0[i] = bi; u1[i] = d1; u2[i] = e1;
          d = ci - m * d1;
          e = -m * e1;
          vv[i] = vnext;
          cv = cv - m * vnext;
        }
      }
      if (fabsf(d) < pivmin) d = (d >= 0.f ? pivmin : -pivmin);
      float vi2 = cv / d;
      vv[N - 1] = vi2;
      float vi1 = (vv[N - 2] - u1[N - 2] * vi2) / u0[N - 2];
      vv[N - 2] = vi1;
      for (int i = N - 3; i >= 0; --i) {
        float t = (vv[i] - u1[i] * vi1 - u2[i] * vi2) / u0[i];
        vv[i] = t;
        vi2 = vi1; vi1 = t;
      }
      float mx = 0.f;
      for (int k = 0; k < N; ++k) mx = fmaxf(mx, fabsf(vv[k]));
      float inv = 1.f / fmaxf(mx, 1e-30f);
      for (int k = 0; k < N; ++k) vv[k] *= inv;
    }
  }
  __syncthreads();

  // ---- MGS orthonormalization (block-parallel) ----
  for (int j = 0; j < RR; ++j) {
    for (int i2 = 0; i2 < j; ++i2) {
      float p_ = 0.f;
      if (tid < N) p_ = S.vt[i2][tid] * S.vt[j][tid];
      float dp = blkReduceSum(p_, S.red, tid);
      if (tid < N) S.vt[j][tid] -= dp * S.vt[i2][tid];
    }
    float p_ = 0.f;
    if (tid < N) p_ = S.vt[j][tid] * S.vt[j][tid];
    float nn = blkReduceSum(p_, S.red, tid);
    float inv = rsqrtf(fmaxf(nn, 1e-33f));
    if (tid < N) S.vt[j][tid] *= inv;
    __syncthreads();
  }

  // ---- back-transform: v = H_0 ... H_{N-3} v; u from ApkL * scl ----
  for (int vec = wid; vec < RR; vec += EIG_WAVES) {
    float* v = &S.vt[vec][0];
    for (int h = N - 3; h >= 0; --h) {
      const float sh = S.scls[h];
      float dp = 0.f;
      for (int k = lane; k < N; k += 64) {
        float uk = (k <= h) ? 0.f : ((k == h + 1) ? 1.f : S.ApkL[((k * (k - 1)) >> 1) + h] * sh);
        dp += uk * v[k];
      }
#pragma unroll
      for (int off = 32; off > 0; off >>= 1) dp += __shfl_down(dp, off, 64);
      dp = __shfl(dp, 0, 64);
      float c = S.taus[h] * dp;
      for (int k = lane; k < N; k += 64) {
        float uk = (k <= h) ? 0.f : ((k == h + 1) ? 1.f : S.ApkL[((k * (k - 1)) >> 1) + h] * sh);
        v[k] -= c * uk;
      }
    }
  }
  __syncthreads();

  // ---- canonical sign (max-|component| positive) + write F (N x RR) ----
  for (int vec = wid; vec < RR; vec += EIG_WAVES) {
    float* v = &S.vt[vec][0];
    float ma = -1.f; int mi = 0x7fffffff;
    for (int k = lane; k < N; k += 64) {
      float a = fabsf(v[k]);
      if (a > ma || (a == ma && k < mi)) { ma = a; mi = k; }
    }
#pragma unroll
    for (int off = 32; off > 0; off >>= 1) {
      float oa = __shfl_down(ma, off, 64);
      int oi = __shfl_down(mi, off, 64);
      if (oa > ma || (oa == ma && oi < mi)) { ma = oa; mi = oi; }
    }
    mi = __shfl(mi, 0, 64);
    float sg = (v[mi] < 0.f) ? -1.f : 1.f;
    for (int k = lane; k < N; k += 64) F[k * RR + vec] = sg * v[k];
  }
}

__global__ __launch_bounds__(EIG_THREADS, 1)
void keigh_init(const float* G0, float* F0, const float* G1, float* F1,
                const float* G2, float* F2, const float* G3, float* F3) {
  __shared__ ESm S;
  if (blockIdx.x == 0)      eig_body<32, 8>(S, G0, F0);
  else if (blockIdx.x == 1) eig_body<100, 6>(S, G1, F1);
  else if (blockIdx.x == 2) eig_body<128, 6>(S, G2, F2);
  else                      eig_body<64, 6>(S, G3, F3);
}

template<int N, int RR>
__global__ __launch_bounds__(EIG_THREADS, 1)
void keigh_one(const float* __restrict__ G, float* __restrict__ F) {
  __shared__ ESm S;
  eig_body<N, RR>(S, G, F);
}

// ---------------------------------------------------------------------------
extern "C" void kernel_launch(void* const* d_in, const int* in_sizes, int n_in,
                              void* d_out, int out_size, void* d_ws, size_t ws_size,
                              hipStream_t stream) {
  (void)in_sizes; (void)n_in; (void)out_size; (void)ws_size;
  const float* x  = (const float*)d_in[0];
  const float* cw = (const float*)d_in[1];
  const float* cb = (const float*)d_in[2];
  float* out = (float*)d_out;
  float* ws  = (float*)d_ws;

  float* T    = ws + OFF_T;
  float* TC   = ws + OFF_TC;
  float* TB   = ws + OFF_TB;
  float* PART = ws + OFF_PART;
  float* TD0a = ws + OFF_TD0a;
  float* TD0b = ws + OFF_TD0b;
  float* TD   = ws + OFF_TD;
  float* G0   = ws + OFF_G0;
  float* G1   = ws + OFF_G1;
  float* G2   = ws + OFF_G2;
  float* G3   = ws + OFF_G3;
  float* F0   = ws + OFF_F0;
  float* F1   = ws + OFF_F1;
  float* F2   = ws + OFF_F2;
  float* F3   = ws + OFF_F3;

  kconv<<<(26214400 + 255) / 256, 256, 0, stream>>>(x, cw, cb, T);

  // ---- HOSVD init: 4 grams, then one batched 4-block eigh ----
  kgram_big<32, 819200, false><<<GRAM_BLOCKS, 256, 0, stream>>>(T, PART, 1);
  kreduce<<<4, 256, 0, stream>>>(PART, G0, 1024);
  kgram_big<100, 8192, false><<<GRAM_BLOCKS, 256, 0, stream>>>(T, PART, 32);
  kreduce<<<40, 256, 0, stream>>>(PART, G1, 10000);
  kgram_big<128, 64, false><<<GRAM_BLOCKS, 256, 0, stream>>>(T, PART, 3200);
  kreduce<<<64, 256, 0, stream>>>(PART, G2, 16384);
  kgram_big<64, 1, true><<<GRAM_BLOCKS, 256, 0, stream>>>(T, PART, 409600);
  kreduce<<<16, 256, 0, stream>>>(PART, G3, 4096);

  keigh_init<<<4, EIG_THREADS, 0, stream>>>(G0, F0, G1, F1, G2, F2, G3, F3);

  // ---- HOOI sweeps ----
  for (int sweep = 0; sweep < 5; ++sweep) {
    // mode 0: Y = T x1 F1 x2 F2 x3 F3 -> (32,6,6,6)
    kcontract<6, 8192><<<1024, 256, 0, stream>>>(T, F1, TB, 32, 100);
    kcontract<6, 64><<<48, 256, 0, stream>>>(TB, F2, TD0a, 192, 128);
    kcontract<6, 1><<<5, 256, 0, stream>>>(TD0a, F3, TD0b, 1152, 64);
    kgram_small<<<4, 256, 0, stream>>>(TD0b, G0, 1, 32, 216);
    keigh_one<32, 8><<<1, EIG_THREADS, 0, stream>>>(G0, F0);
    // TC = T x0 F0 (reused by modes 1,2,3 and the final core)
    kcontract<8, 819200><<<3200, 256, 0, stream>>>(T, F0, TC, 1, 32);
    // mode 1
    kcontract<6, 64><<<200, 256, 0, stream>>>(TC, F2, TB, 800, 128);
    kcontract<6, 1><<<19, 256, 0, stream>>>(TB, F3, TD, 4800, 64);
    kgram_small<<<40, 256, 0, stream>>>(TD, G0, 8, 100, 36);
    keigh_one<100, 6><<<1, EIG_THREADS, 0, stream>>>(G0, F1);
    // mode 2 (TB = TC x1 F1 also reused by mode 3)
    kcontract<6, 8192><<<256, 256, 0, stream>>>(TC, F1, TB, 8, 100);
    kcontract<6, 1><<<24, 256, 0, stream>>>(TB, F3, TD, 6144, 64);
    kgram_small<<<64, 256, 0, stream>>>(TD, G0, 48, 128, 6);
    keigh_one<128, 6><<<1, EIG_THREADS, 0, stream>>>(G0, F2);
    // mode 3 (reuses TB from mode 2)
    kcontract<6, 64><<<12, 256, 0, stream>>>(TB, F2, TD, 48, 128);
    kgram_small<<<16, 256, 0, stream>>>(TD, G0, 288, 64, 1);
    keigh_one<64, 6><<<1, EIG_THREADS, 0, stream>>>(G0, F3);
  }

  // ---- core = (TC) x1 F1 x2 F2 x3 F3 -> (8,6,6,6) ----
  kcontract<6, 8192><<<256, 256, 0, stream>>>(TC, F1, TB, 8, 100);
  kcontract<6, 64><<<12, 256, 0, stream>>>(TB, F2, TD, 48, 128);
  kcontract<6, 1><<<2, 256, 0, stream>>>(TD, F3, out, 288, 64);
}